// Round 3
// baseline (437.620 us; speedup 1.0000x reference)
//
#include <hip/hip_runtime.h>
#include <stdint.h>

// ---------- types ----------
typedef __attribute__((ext_vector_type(8))) _Float16 half8;
typedef __attribute__((ext_vector_type(2))) __fp16   fp16x2;
typedef __attribute__((ext_vector_type(4))) float    f32x4;
typedef __attribute__((ext_vector_type(4))) unsigned short us4;

__device__ __forceinline__ unsigned short f2h(float f) {
  union { _Float16 h; unsigned short u; } cv; cv.h = (_Float16)f; return cv.u;
}

// async global->LDS, 16B per lane. lds base wave-uniform; HW adds lane*16.
__device__ __forceinline__ void async_copy16(void* lds, const void* g) {
  __builtin_amdgcn_global_load_lds(
      (__attribute__((address_space(1))) void*)(void*)g,
      (__attribute__((address_space(3))) void*)lds, 16, 0, 0);
}

union U64 { fp16x2 h2[2]; us4 u4; };

// ---------- fused f32 -> f16 conversion (7 regions, 1 launch) ----------
__global__ __launch_bounds__(256) void cvt_all(
    const float* __restrict__ q, const float* __restrict__ k, const float* __restrict__ v,
    const float* __restrict__ wq, const float* __restrict__ wk,
    const float* __restrict__ wv, const float* __restrict__ wo,
    unsigned short* __restrict__ oq, unsigned short* __restrict__ ok,
    unsigned short* __restrict__ ov,
    unsigned short* __restrict__ owq, unsigned short* __restrict__ owk,
    unsigned short* __restrict__ owv, unsigned short* __restrict__ owo) {
  int b = blockIdx.x;
  const float* in; unsigned short* out;
  if      (b < 8192)  { in = q;  out = oq;             }
  else if (b < 16384) { in = k;  out = ok;  b -= 8192; }
  else if (b < 24576) { in = v;  out = ov;  b -= 16384; }
  else if (b < 25600) { in = wq; out = owq; b -= 24576; }
  else if (b < 26624) { in = wk; out = owk; b -= 25600; }
  else if (b < 27648) { in = wv; out = owv; b -= 26624; }
  else                { in = wo; out = owo; b -= 27648; }
  const int i = (b * 256 + threadIdx.x) * 4;
  const float4 x = *(const float4*)(in + i);
  us4 o; o.x = f2h(x.x); o.y = f2h(x.y); o.z = f2h(x.z); o.w = f2h(x.w);
  *(us4*)(out + i) = o;
}

// ---------- 128x128 tile GEMM core: C = A(MxK) * W(NxK)^T, K=1024, BK=32 ----------
__device__ __forceinline__ void gemm128_core(const unsigned short* __restrict__ A,
                                             const unsigned short* __restrict__ Bw,
                                             int m0, int n0,
                                             unsigned short* As, unsigned short* Bs,
                                             f32x4 acc[4][4]) {
  const int tid  = threadIdx.x;
  const int w    = tid >> 6;
  const int l15  = tid & 15;
  const int quad = (tid >> 4) & 3;
  const int w0 = w & 1, w1 = w >> 1;
  const f32x4 zero4 = {0.f, 0.f, 0.f, 0.f};
#pragma unroll
  for (int mt = 0; mt < 4; ++mt)
#pragma unroll
    for (int nt = 0; nt < 4; ++nt) acc[mt][nt] = zero4;

  int srcR[2], srcC[2];
#pragma unroll
  for (int c = 0; c < 2; ++c) {
    const int idx = c * 256 + tid;
    srcR[c] = idx >> 2;
    srcC[c] = (idx & 3) ^ (srcR[c] & 3) ^ ((srcR[c] >> 2) & 3);
  }
  const int cs = quad ^ (l15 & 3) ^ (l15 >> 2);

  for (int k0 = 0; k0 < 1024; k0 += 32) {
    __syncthreads();
#pragma unroll
    for (int c = 0; c < 2; ++c) {
      async_copy16((char*)As + c * 4096 + w * 1024,
                   A  + (m0 + srcR[c]) * 1024 + k0 + srcC[c] * 8);
      async_copy16((char*)Bs + c * 4096 + w * 1024,
                   Bw + (n0 + srcR[c]) * 1024 + k0 + srcC[c] * 8);
    }
    __syncthreads();
    half8 af[4], bf[4];
#pragma unroll
    for (int mt = 0; mt < 4; ++mt)
      af[mt] = *(const half8*)(As + (w1 * 64 + mt * 16 + l15) * 32 + cs * 8);
#pragma unroll
    for (int nt = 0; nt < 4; ++nt)
      bf[nt] = *(const half8*)(Bs + (w0 * 64 + nt * 16 + l15) * 32 + cs * 8);
#pragma unroll
    for (int mt = 0; mt < 4; ++mt)
#pragma unroll
      for (int nt = 0; nt < 4; ++nt)
        acc[mt][nt] = __builtin_amdgcn_mfma_f32_16x16x32_f16(af[mt], bf[nt], acc[mt][nt], 0, 0, 0);
  }
}

// ---------- QKV projection; z selects Q/K/V. Q is pre-scaled by 0.125*log2(e). ----------
__global__ __launch_bounds__(256) void gemm_qkv(
    const unsigned short* __restrict__ Xq, const unsigned short* __restrict__ Xk,
    const unsigned short* __restrict__ Xv,
    const unsigned short* __restrict__ Wq, const unsigned short* __restrict__ Wk,
    const unsigned short* __restrict__ Wv,
    const float* __restrict__ bq, const float* __restrict__ bk, const float* __restrict__ bv,
    unsigned short* __restrict__ Qo, unsigned short* __restrict__ Ko,
    unsigned short* __restrict__ Vo) {
  __shared__ __align__(16) unsigned short As[128 * 32];
  __shared__ __align__(16) unsigned short Bs[128 * 32];
  const int z = blockIdx.z;
  const unsigned short* A = (z == 0) ? Xq : (z == 1) ? Xk : Xv;
  const unsigned short* W = (z == 0) ? Wq : (z == 1) ? Wk : Wv;
  const float* bias = (z == 0) ? bq : (z == 1) ? bk : bv;
  const int m0 = blockIdx.x * 128, n0 = blockIdx.y * 128;
  f32x4 acc[4][4];
  gemm128_core(A, W, m0, n0, As, Bs, acc);

  const int tid = threadIdx.x;
  const int w = tid >> 6, l15 = tid & 15, quad = (tid >> 4) & 3;
  const int w0 = w & 1, w1 = w >> 1;
  const float qscale = (z == 0) ? 0.18033688011112042f : 1.0f;  // 0.125*log2(e)
#pragma unroll
  for (int mt = 0; mt < 4; ++mt) {
    const int mbase = m0 + w1 * 64 + mt * 16 + quad * 4;  // global row = b*2048+s
    const int bb = mbase >> 11, s = mbase & 2047;
#pragma unroll
    for (int nt = 0; nt < 4; ++nt) {
      const int col = n0 + w0 * 64 + nt * 16 + l15;
      const float badd = bias[col];
      const int h = col >> 6, d = col & 63;
      if (z < 2) {
        unsigned short* dst = (z == 0) ? Qo : Ko;
#pragma unroll
        for (int r = 0; r < 4; ++r)
          dst[((bb * 16 + h) * 2048 + (s + r)) * 64 + d] = f2h((acc[mt][nt][r] + badd) * qscale);
      } else {
        us4 pk;
#pragma unroll
        for (int r = 0; r < 4; ++r) pk[r] = f2h(acc[mt][nt][r] + badd);
        *(us4*)(Vo + ((bb * 16 + h) * 64 + d) * 2048 + s) = pk;
      }
    }
  }
}

// ---------- flash attention, transposed-score orientation, 8-wave blocks ----------
// grid (64 bh, 8 qtiles) x 512 threads. bh on blockIdx.x so all 8 q-tile blocks of
// a bh land on ONE XCD (linear id % 8 == bh % 8): K/V stream once per XCD L2
// instead of thrashing (round-2 FETCH was 139MB vs 48MB ideal -> K/V re-fetched 4x).
// Q is loaded DIRECT to registers (the LDS swizzle cancels: frag d = quad*8(+32)),
// and P^T is h-split (32-key halves, PKS=40): LDS = 53,248B -> 3 blocks/CU
// (24 waves/CU, was 16). S^T = K*Q^T so C-layout col = q-row = l15 everywhere;
// row sums via ones-A-frag MFMA; no shuffles. K/V double-buffered, one
// __syncthreads per tile (implicit vmcnt(0) drains next tile AFTER the MFMAs).
#define PKS 40  // P^T key stride (halves) for a 32-key half: 80B rows, 16B-aligned
__global__ __launch_bounds__(512, 6) void attn_kernel(const unsigned short* __restrict__ Q,
                                                      const unsigned short* __restrict__ K,
                                                      const unsigned short* __restrict__ Vt,
                                                      unsigned short* __restrict__ O) {
  __shared__ __align__(16) unsigned short Ps[10240];       // 20,480B: P^T strips, 1280/wave
  __shared__ __align__(16) unsigned short Ks[2][64 * 64];  // double-buffered
  __shared__ __align__(16) unsigned short Vs[2][64 * 64];  // [d][key], double-buffered
  const int bh = blockIdx.x, qt = blockIdx.y;
  const int tid = threadIdx.x;
  const int w = tid >> 6, l15 = tid & 15, quad = (tid >> 4) & 3;
  const int cq0 = quad ^ (l15 & 7), cq1 = (4 + quad) ^ (l15 & 7);

  // K/V tile staging: 512 threads x 16B = one full 64x64 f16 tile per instr.
  const int srcR = tid >> 3;
  const int srcC = (tid & 7) ^ (srcR & 7);

  const unsigned short* Kg0 = K + bh * 2048 * 64;
  const unsigned short* Vg0 = Vt + bh * 131072;

  auto stage_kv = [&](int t, int buf) {
    async_copy16((char*)Ks + buf * 8192 + w * 1024, Kg0 + t * 4096 + srcR * 64 + srcC * 8);
    async_copy16((char*)Vs + buf * 8192 + w * 1024, Vg0 + t * 64 + srcR * 2048 + srcC * 8);
  };

  // Q B-frags direct from global: qf[s][h] = Q[row][h*32 + quad*8 .. +7], 16B aligned.
  stage_kv(0, 0);
  const unsigned short* Qg = Q + (bh * 2048 + qt * 256) * 64;
  half8 qf[2][2];
#pragma unroll
  for (int s = 0; s < 2; ++s) {
    const int row = w * 32 + s * 16 + l15;
    qf[s][0] = *(const half8*)(Qg + row * 64 + quad * 8);
    qf[s][1] = *(const half8*)(Qg + row * 64 + 32 + quad * 8);
  }
  __syncthreads();  // drain K/V tile0

  const f32x4 zero4 = {0.f, 0.f, 0.f, 0.f};
  f32x4 acc[2][4];   // O^T: acc[strip][dt], rows d=dt*16+quad*4+r, col qrow=l15
  f32x4 lsum[2];
#pragma unroll
  for (int s = 0; s < 2; ++s) {
    lsum[s] = zero4;
#pragma unroll
    for (int dt = 0; dt < 4; ++dt) acc[s][dt] = zero4;
  }
  half8 ones;
#pragma unroll
  for (int i = 0; i < 8; ++i) ones[i] = (_Float16)1.0f;

  unsigned short* Pw = Ps + w * 1280;  // 2 strips x 16 x PKS halves, wave-private

  for (int kt = 0; kt < 32; ++kt) {
    if (kt < 31) stage_kv(kt + 1, (kt + 1) & 1);  // issue next tile NOW; drains at barrier below
    const unsigned short* Kc = Ks[kt & 1];
    const unsigned short* Vc = Vs[kt & 1];

    // per 32-key half: S^T (2 nt) -> exp2 -> P^T half-buffer -> PV for that half.
#pragma unroll
    for (int h = 0; h < 2; ++h) {
#pragma unroll
      for (int nt2 = 0; nt2 < 2; ++nt2) {
        const int rk = (h * 2 + nt2) * 16 + l15;
        half8 ak0 = *(const half8*)(Kc + rk * 64 + cq0 * 8);
        half8 ak1 = *(const half8*)(Kc + rk * 64 + cq1 * 8);
#pragma unroll
        for (int s = 0; s < 2; ++s) {
          f32x4 z = zero4;
          z = __builtin_amdgcn_mfma_f32_16x16x32_f16(ak0, qf[s][0], z, 0, 0, 0);
          z = __builtin_amdgcn_mfma_f32_16x16x32_f16(ak1, qf[s][1], z, 0, 0, 0);
          U64 u;
          u.h2[0] = __builtin_amdgcn_cvt_pkrtz(__builtin_exp2f(z[0]), __builtin_exp2f(z[1]));
          u.h2[1] = __builtin_amdgcn_cvt_pkrtz(__builtin_exp2f(z[2]), __builtin_exp2f(z[3]));
          // keys (within half) nt2*16+quad*4+r at P^T[strip][qrow=l15][key]
          *(us4*)(Pw + s * 640 + l15 * PKS + nt2 * 16 + quad * 4) = u.u4;
        }
      }
      // PV for this 32-key half: O^T += V^T * P^T ; l via ones-A-frag MFMA
      const int ch = h ? cq1 : cq0;
      half8 bp[2];
#pragma unroll
      for (int s = 0; s < 2; ++s) {
        bp[s] = *(const half8*)(Pw + s * 640 + l15 * PKS + quad * 8);
        lsum[s] = __builtin_amdgcn_mfma_f32_16x16x32_f16(ones, bp[s], lsum[s], 0, 0, 0);
      }
#pragma unroll
      for (int dt = 0; dt < 4; ++dt) {
        half8 av = *(const half8*)(Vc + (dt * 16 + l15) * 64 + ch * 8);
#pragma unroll
        for (int s = 0; s < 2; ++s)
          acc[s][dt] = __builtin_amdgcn_mfma_f32_16x16x32_f16(av, bp[s], acc[s][dt], 0, 0, 0);
      }
    }
    __syncthreads();  // drains next-tile loads (vmcnt 0) + protects K/V buffers
  }

  // epilogue: O (B,S,1024) f16; col(l15)=qrow for both acc and lsum -> no shuffles
  const int b = bh >> 4, hd = bh & 15;
#pragma unroll
  for (int s = 0; s < 2; ++s) {
    const float rv = 1.0f / lsum[s][0];
    const int sg = qt * 256 + w * 32 + s * 16 + l15;
    unsigned short* Orow = O + (b * 2048 + sg) * 1024 + hd * 64;
#pragma unroll
    for (int dt = 0; dt < 4; ++dt) {
      U64 u;
      u.h2[0] = __builtin_amdgcn_cvt_pkrtz(acc[s][dt][0] * rv, acc[s][dt][1] * rv);
      u.h2[1] = __builtin_amdgcn_cvt_pkrtz(acc[s][dt][2] * rv, acc[s][dt][3] * rv);
      *(us4*)(Orow + dt * 16 + quad * 4) = u.u4;
    }
  }
}

// ---------- output projection -> f32 ----------
__global__ __launch_bounds__(256) void gemm_out(const unsigned short* __restrict__ A,
                                                const unsigned short* __restrict__ W,
                                                const float* __restrict__ bias,
                                                float* __restrict__ out) {
  __shared__ __align__(16) unsigned short As[128 * 32];
  __shared__ __align__(16) unsigned short Bs[128 * 32];
  const int m0 = blockIdx.x * 128, n0 = blockIdx.y * 128;
  f32x4 acc[4][4];
  gemm128_core(A, W, m0, n0, As, Bs, acc);
  const int tid = threadIdx.x;
  const int w = tid >> 6, l15 = tid & 15, quad = (tid >> 4) & 3;
  const int w0 = w & 1, w1 = w >> 1;
#pragma unroll
  for (int mt = 0; mt < 4; ++mt) {
    const int mbase = m0 + w1 * 64 + mt * 16 + quad * 4;
#pragma unroll
    for (int nt = 0; nt < 4; ++nt) {
      const int col = n0 + w0 * 64 + nt * 16 + l15;
      const float badd = bias[col];
#pragma unroll
      for (int r = 0; r < 4; ++r)
        out[(mbase + r) * 1024 + col] = acc[mt][nt][r] + badd;
    }
  }
}

// ---------- launch ----------
extern "C" void kernel_launch(void* const* d_in, const int* in_sizes, int n_in,
                              void* d_out, int out_size, void* d_ws, size_t ws_size,
                              hipStream_t stream) {
  const float* query = (const float*)d_in[0];
  const float* key_  = (const float*)d_in[1];
  const float* value = (const float*)d_in[2];
  const float* Wq = (const float*)d_in[3];
  const float* bq = (const float*)d_in[4];
  const float* Wk = (const float*)d_in[5];
  const float* bk = (const float*)d_in[6];
  const float* Wv = (const float*)d_in[7];
  const float* bv = (const float*)d_in[8];
  const float* Wo = (const float*)d_in[9];
  const float* bo = (const float*)d_in[10];

  unsigned short* ws = (unsigned short*)d_ws;
  unsigned short* xq = ws;               // (B,S,D) f16 of query
  unsigned short* xk = xq + 8388608;
  unsigned short* xv = xk + 8388608;
  unsigned short* wq = xv + 8388608;
  unsigned short* wk = wq + 1048576;
  unsigned short* wv = wk + 1048576;
  unsigned short* wo = wv + 1048576;
  unsigned short* Qw = wo + 1048576;     // (B,H,S,64), pre-scaled by 0.125*log2e
  unsigned short* Kw = Qw + 8388608;     // (B,H,S,64)
  unsigned short* Vw = Kw + 8388608;     // (B,H,64,S) transposed
  unsigned short* Ow = xq;               // reuse query-f16 region for attn output

  cvt_all<<<28672, 256, 0, stream>>>(query, key_, value, Wq, Wk, Wv, Wo,
                                     xq, xk, xv, wq, wk, wv, wo);
  gemm_qkv<<<dim3(64, 8, 3), 256, 0, stream>>>(xq, xk, xv, wq, wk, wv, bq, bk, bv, Qw, Kw, Vw);
  attn_kernel<<<dim3(64, 8), 512, 0, stream>>>(Qw, Kw, Vw, Ow);
  gemm_out<<<dim3(64, 8), 256, 0, stream>>>(Ow, wo, bo, (float*)d_out);
}

// Round 4
// 356.960 us; speedup vs baseline: 1.2260x; 1.2260x over previous
//
#include <hip/hip_runtime.h>
#include <stdint.h>

// ---------- types ----------
typedef __attribute__((ext_vector_type(8))) _Float16 half8;
typedef __attribute__((ext_vector_type(2))) __fp16   fp16x2;
typedef __attribute__((ext_vector_type(4))) float    f32x4;
typedef __attribute__((ext_vector_type(4))) unsigned short us4;

__device__ __forceinline__ unsigned short f2h(float f) {
  union { _Float16 h; unsigned short u; } cv; cv.h = (_Float16)f; return cv.u;
}

// async global->LDS, 16B per lane. lds base wave-uniform; HW adds lane*16.
__device__ __forceinline__ void async_copy16(void* lds, const void* g) {
  __builtin_amdgcn_global_load_lds(
      (__attribute__((address_space(1))) void*)(void*)g,
      (__attribute__((address_space(3))) void*)lds, 16, 0, 0);
}

union U64 { fp16x2 h2[2]; us4 u4; };

// ---------- fused f32 -> f16 conversion (7 regions, 1 launch) ----------
__global__ __launch_bounds__(256) void cvt_all(
    const float* __restrict__ q, const float* __restrict__ k, const float* __restrict__ v,
    const float* __restrict__ wq, const float* __restrict__ wk,
    const float* __restrict__ wv, const float* __restrict__ wo,
    unsigned short* __restrict__ oq, unsigned short* __restrict__ ok,
    unsigned short* __restrict__ ov,
    unsigned short* __restrict__ owq, unsigned short* __restrict__ owk,
    unsigned short* __restrict__ owv, unsigned short* __restrict__ owo) {
  int b = blockIdx.x;
  const float* in; unsigned short* out;
  if      (b < 8192)  { in = q;  out = oq;             }
  else if (b < 16384) { in = k;  out = ok;  b -= 8192; }
  else if (b < 24576) { in = v;  out = ov;  b -= 16384; }
  else if (b < 25600) { in = wq; out = owq; b -= 24576; }
  else if (b < 26624) { in = wk; out = owk; b -= 25600; }
  else if (b < 27648) { in = wv; out = owv; b -= 26624; }
  else                { in = wo; out = owo; b -= 27648; }
  const int i = (b * 256 + threadIdx.x) * 4;
  const float4 x = *(const float4*)(in + i);
  us4 o; o.x = f2h(x.x); o.y = f2h(x.y); o.z = f2h(x.z); o.w = f2h(x.w);
  *(us4*)(out + i) = o;
}

// ---------- 128x128 tile GEMM core: C = A(MxK) * W(NxK)^T, K=1024, BK=32 ----------
__device__ __forceinline__ void gemm128_core(const unsigned short* __restrict__ A,
                                             const unsigned short* __restrict__ Bw,
                                             int m0, int n0,
                                             unsigned short* As, unsigned short* Bs,
                                             f32x4 acc[4][4]) {
  const int tid  = threadIdx.x;
  const int w    = tid >> 6;
  const int l15  = tid & 15;
  const int quad = (tid >> 4) & 3;
  const int w0 = w & 1, w1 = w >> 1;
  const f32x4 zero4 = {0.f, 0.f, 0.f, 0.f};
#pragma unroll
  for (int mt = 0; mt < 4; ++mt)
#pragma unroll
    for (int nt = 0; nt < 4; ++nt) acc[mt][nt] = zero4;

  int srcR[2], srcC[2];
#pragma unroll
  for (int c = 0; c < 2; ++c) {
    const int idx = c * 256 + tid;
    srcR[c] = idx >> 2;
    srcC[c] = (idx & 3) ^ (srcR[c] & 3) ^ ((srcR[c] >> 2) & 3);
  }
  const int cs = quad ^ (l15 & 3) ^ (l15 >> 2);

  for (int k0 = 0; k0 < 1024; k0 += 32) {
    __syncthreads();
#pragma unroll
    for (int c = 0; c < 2; ++c) {
      async_copy16((char*)As + c * 4096 + w * 1024,
                   A  + (m0 + srcR[c]) * 1024 + k0 + srcC[c] * 8);
      async_copy16((char*)Bs + c * 4096 + w * 1024,
                   Bw + (n0 + srcR[c]) * 1024 + k0 + srcC[c] * 8);
    }
    __syncthreads();
    half8 af[4], bf[4];
#pragma unroll
    for (int mt = 0; mt < 4; ++mt)
      af[mt] = *(const half8*)(As + (w1 * 64 + mt * 16 + l15) * 32 + cs * 8);
#pragma unroll
    for (int nt = 0; nt < 4; ++nt)
      bf[nt] = *(const half8*)(Bs + (w0 * 64 + nt * 16 + l15) * 32 + cs * 8);
#pragma unroll
    for (int mt = 0; mt < 4; ++mt)
#pragma unroll
      for (int nt = 0; nt < 4; ++nt)
        acc[mt][nt] = __builtin_amdgcn_mfma_f32_16x16x32_f16(af[mt], bf[nt], acc[mt][nt], 0, 0, 0);
  }
}

// ---------- QKV projection; z selects Q/K/V. Q is pre-scaled by 0.125*log2(e). ----------
__global__ __launch_bounds__(256) void gemm_qkv(
    const unsigned short* __restrict__ Xq, const unsigned short* __restrict__ Xk,
    const unsigned short* __restrict__ Xv,
    const unsigned short* __restrict__ Wq, const unsigned short* __restrict__ Wk,
    const unsigned short* __restrict__ Wv,
    const float* __restrict__ bq, const float* __restrict__ bk, const float* __restrict__ bv,
    unsigned short* __restrict__ Qo, unsigned short* __restrict__ Ko,
    unsigned short* __restrict__ Vo) {
  __shared__ __align__(16) unsigned short As[128 * 32];
  __shared__ __align__(16) unsigned short Bs[128 * 32];
  const int z = blockIdx.z;
  const unsigned short* A = (z == 0) ? Xq : (z == 1) ? Xk : Xv;
  const unsigned short* W = (z == 0) ? Wq : (z == 1) ? Wk : Wv;
  const float* bias = (z == 0) ? bq : (z == 1) ? bk : bv;
  const int m0 = blockIdx.x * 128, n0 = blockIdx.y * 128;
  f32x4 acc[4][4];
  gemm128_core(A, W, m0, n0, As, Bs, acc);

  const int tid = threadIdx.x;
  const int w = tid >> 6, l15 = tid & 15, quad = (tid >> 4) & 3;
  const int w0 = w & 1, w1 = w >> 1;
  const float qscale = (z == 0) ? 0.18033688011112042f : 1.0f;  // 0.125*log2(e)
#pragma unroll
  for (int mt = 0; mt < 4; ++mt) {
    const int mbase = m0 + w1 * 64 + mt * 16 + quad * 4;  // global row = b*2048+s
    const int bb = mbase >> 11, s = mbase & 2047;
#pragma unroll
    for (int nt = 0; nt < 4; ++nt) {
      const int col = n0 + w0 * 64 + nt * 16 + l15;
      const float badd = bias[col];
      const int h = col >> 6, d = col & 63;
      if (z < 2) {
        unsigned short* dst = (z == 0) ? Qo : Ko;
#pragma unroll
        for (int r = 0; r < 4; ++r)
          dst[((bb * 16 + h) * 2048 + (s + r)) * 64 + d] = f2h((acc[mt][nt][r] + badd) * qscale);
      } else {
        us4 pk;
#pragma unroll
        for (int r = 0; r < 4; ++r) pk[r] = f2h(acc[mt][nt][r] + badd);
        *(us4*)(Vo + ((bb * 16 + h) * 64 + d) * 2048 + s) = pk;
      }
    }
  }
}

// ---------- flash attention, transposed-score orientation, 8-wave blocks ----------
// grid (64 bh, 8 qtiles) x 512 threads. bh on blockIdx.x so all 8 q-tile blocks of
// a bh land on ONE XCD (linear id % 8 == bh % 8): K/V stream once per XCD L2.
// Q is loaded DIRECT to registers (the LDS swizzle cancels: frag d = quad*8(+32)),
// and P^T is h-split (32-key halves, PKS=40): LDS = 53,248B -> 3 blocks/CU.
// __launch_bounds__(512, 4): round-3's (512,6) forced VGPR to 40 < the ~56 live
// registers -> accumulator SPILL to scratch (WRITE_SIZE 16->276MB, MfmaUtil 15%).
// 4 waves/EU min keeps the 128-VGPR budget; compiler lands ~64, no spill; LDS is
// then the occupancy limiter at 3 blocks/CU (6 waves/SIMD).
// S^T = K*Q^T so C-layout col = q-row = l15 everywhere; row sums via ones-A-frag
// MFMA; no shuffles. K/V double-buffered, one __syncthreads per tile (implicit
// vmcnt(0) drains next tile AFTER the MFMAs).
#define PKS 40  // P^T key stride (halves) for a 32-key half: 80B rows, 16B-aligned
__global__ __launch_bounds__(512, 4) void attn_kernel(const unsigned short* __restrict__ Q,
                                                      const unsigned short* __restrict__ K,
                                                      const unsigned short* __restrict__ Vt,
                                                      unsigned short* __restrict__ O) {
  __shared__ __align__(16) unsigned short Ps[10240];       // 20,480B: P^T strips, 1280/wave
  __shared__ __align__(16) unsigned short Ks[2][64 * 64];  // double-buffered
  __shared__ __align__(16) unsigned short Vs[2][64 * 64];  // [d][key], double-buffered
  const int bh = blockIdx.x, qt = blockIdx.y;
  const int tid = threadIdx.x;
  const int w = tid >> 6, l15 = tid & 15, quad = (tid >> 4) & 3;
  const int cq0 = quad ^ (l15 & 7), cq1 = (4 + quad) ^ (l15 & 7);

  // K/V tile staging: 512 threads x 16B = one full 64x64 f16 tile per instr.
  const int srcR = tid >> 3;
  const int srcC = (tid & 7) ^ (srcR & 7);

  const unsigned short* Kg0 = K + bh * 2048 * 64;
  const unsigned short* Vg0 = Vt + bh * 131072;

  auto stage_kv = [&](int t, int buf) {
    async_copy16((char*)Ks + buf * 8192 + w * 1024, Kg0 + t * 4096 + srcR * 64 + srcC * 8);
    async_copy16((char*)Vs + buf * 8192 + w * 1024, Vg0 + t * 64 + srcR * 2048 + srcC * 8);
  };

  // Q B-frags direct from global: qf[s][h] = Q[row][h*32 + quad*8 .. +7], 16B aligned.
  stage_kv(0, 0);
  const unsigned short* Qg = Q + (bh * 2048 + qt * 256) * 64;
  half8 qf[2][2];
#pragma unroll
  for (int s = 0; s < 2; ++s) {
    const int row = w * 32 + s * 16 + l15;
    qf[s][0] = *(const half8*)(Qg + row * 64 + quad * 8);
    qf[s][1] = *(const half8*)(Qg + row * 64 + 32 + quad * 8);
  }
  __syncthreads();  // drain K/V tile0

  const f32x4 zero4 = {0.f, 0.f, 0.f, 0.f};
  f32x4 acc[2][4];   // O^T: acc[strip][dt], rows d=dt*16+quad*4+r, col qrow=l15
  f32x4 lsum[2];
#pragma unroll
  for (int s = 0; s < 2; ++s) {
    lsum[s] = zero4;
#pragma unroll
    for (int dt = 0; dt < 4; ++dt) acc[s][dt] = zero4;
  }
  half8 ones;
#pragma unroll
  for (int i = 0; i < 8; ++i) ones[i] = (_Float16)1.0f;

  unsigned short* Pw = Ps + w * 1280;  // 2 strips x 16 x PKS halves, wave-private

  for (int kt = 0; kt < 32; ++kt) {
    if (kt < 31) stage_kv(kt + 1, (kt + 1) & 1);  // issue next tile NOW; drains at barrier below
    const unsigned short* Kc = Ks[kt & 1];
    const unsigned short* Vc = Vs[kt & 1];

    // per 32-key half: S^T (2 nt) -> exp2 -> P^T half-buffer -> PV for that half.
#pragma unroll
    for (int h = 0; h < 2; ++h) {
#pragma unroll
      for (int nt2 = 0; nt2 < 2; ++nt2) {
        const int rk = (h * 2 + nt2) * 16 + l15;
        half8 ak0 = *(const half8*)(Kc + rk * 64 + cq0 * 8);
        half8 ak1 = *(const half8*)(Kc + rk * 64 + cq1 * 8);
#pragma unroll
        for (int s = 0; s < 2; ++s) {
          f32x4 z = zero4;
          z = __builtin_amdgcn_mfma_f32_16x16x32_f16(ak0, qf[s][0], z, 0, 0, 0);
          z = __builtin_amdgcn_mfma_f32_16x16x32_f16(ak1, qf[s][1], z, 0, 0, 0);
          U64 u;
          u.h2[0] = __builtin_amdgcn_cvt_pkrtz(__builtin_exp2f(z[0]), __builtin_exp2f(z[1]));
          u.h2[1] = __builtin_amdgcn_cvt_pkrtz(__builtin_exp2f(z[2]), __builtin_exp2f(z[3]));
          // keys (within half) nt2*16+quad*4+r at P^T[strip][qrow=l15][key]
          *(us4*)(Pw + s * 640 + l15 * PKS + nt2 * 16 + quad * 4) = u.u4;
        }
      }
      // PV for this 32-key half: O^T += V^T * P^T ; l via ones-A-frag MFMA
      const int ch = h ? cq1 : cq0;
      half8 bp[2];
#pragma unroll
      for (int s = 0; s < 2; ++s) {
        bp[s] = *(const half8*)(Pw + s * 640 + l15 * PKS + quad * 8);
        lsum[s] = __builtin_amdgcn_mfma_f32_16x16x32_f16(ones, bp[s], lsum[s], 0, 0, 0);
      }
#pragma unroll
      for (int dt = 0; dt < 4; ++dt) {
        half8 av = *(const half8*)(Vc + (dt * 16 + l15) * 64 + ch * 8);
#pragma unroll
        for (int s = 0; s < 2; ++s)
          acc[s][dt] = __builtin_amdgcn_mfma_f32_16x16x32_f16(av, bp[s], acc[s][dt], 0, 0, 0);
      }
    }
    __syncthreads();  // drains next-tile loads (vmcnt 0) + protects K/V buffers
  }

  // epilogue: O (B,S,1024) f16; col(l15)=qrow for both acc and lsum -> no shuffles
  const int b = bh >> 4, hd = bh & 15;
#pragma unroll
  for (int s = 0; s < 2; ++s) {
    const float rv = 1.0f / lsum[s][0];
    const int sg = qt * 256 + w * 32 + s * 16 + l15;
    unsigned short* Orow = O + (b * 2048 + sg) * 1024 + hd * 64;
#pragma unroll
    for (int dt = 0; dt < 4; ++dt) {
      U64 u;
      u.h2[0] = __builtin_amdgcn_cvt_pkrtz(acc[s][dt][0] * rv, acc[s][dt][1] * rv);
      u.h2[1] = __builtin_amdgcn_cvt_pkrtz(acc[s][dt][2] * rv, acc[s][dt][3] * rv);
      *(us4*)(Orow + dt * 16 + quad * 4) = u.u4;
    }
  }
}

// ---------- output projection -> f32 ----------
__global__ __launch_bounds__(256) void gemm_out(const unsigned short* __restrict__ A,
                                                const unsigned short* __restrict__ W,
                                                const float* __restrict__ bias,
                                                float* __restrict__ out) {
  __shared__ __align__(16) unsigned short As[128 * 32];
  __shared__ __align__(16) unsigned short Bs[128 * 32];
  const int m0 = blockIdx.x * 128, n0 = blockIdx.y * 128;
  f32x4 acc[4][4];
  gemm128_core(A, W, m0, n0, As, Bs, acc);
  const int tid = threadIdx.x;
  const int w = tid >> 6, l15 = tid & 15, quad = (tid >> 4) & 3;
  const int w0 = w & 1, w1 = w >> 1;
#pragma unroll
  for (int mt = 0; mt < 4; ++mt) {
    const int mbase = m0 + w1 * 64 + mt * 16 + quad * 4;
#pragma unroll
    for (int nt = 0; nt < 4; ++nt) {
      const int col = n0 + w0 * 64 + nt * 16 + l15;
      const float badd = bias[col];
#pragma unroll
      for (int r = 0; r < 4; ++r)
        out[(mbase + r) * 1024 + col] = acc[mt][nt][r] + badd;
    }
  }
}

// ---------- launch ----------
extern "C" void kernel_launch(void* const* d_in, const int* in_sizes, int n_in,
                              void* d_out, int out_size, void* d_ws, size_t ws_size,
                              hipStream_t stream) {
  const float* query = (const float*)d_in[0];
  const float* key_  = (const float*)d_in[1];
  const float* value = (const float*)d_in[2];
  const float* Wq = (const float*)d_in[3];
  const float* bq = (const float*)d_in[4];
  const float* Wk = (const float*)d_in[5];
  const float* bk = (const float*)d_in[6];
  const float* Wv = (const float*)d_in[7];
  const float* bv = (const float*)d_in[8];
  const float* Wo = (const float*)d_in[9];
  const float* bo = (const float*)d_in[10];

  unsigned short* ws = (unsigned short*)d_ws;
  unsigned short* xq = ws;               // (B,S,D) f16 of query
  unsigned short* xk = xq + 8388608;
  unsigned short* xv = xk + 8388608;
  unsigned short* wq = xv + 8388608;
  unsigned short* wk = wq + 1048576;
  unsigned short* wv = wk + 1048576;
  unsigned short* wo = wv + 1048576;
  unsigned short* Qw = wo + 1048576;     // (B,H,S,64), pre-scaled by 0.125*log2e
  unsigned short* Kw = Qw + 8388608;     // (B,H,S,64)
  unsigned short* Vw = Kw + 8388608;     // (B,H,64,S) transposed
  unsigned short* Ow = xq;               // reuse query-f16 region for attn output

  cvt_all<<<28672, 256, 0, stream>>>(query, key_, value, Wq, Wk, Wv, Wo,
                                     xq, xk, xv, wq, wk, wv, wo);
  gemm_qkv<<<dim3(64, 8, 3), 256, 0, stream>>>(xq, xk, xv, wq, wk, wv, bq, bk, bv, Qw, Kw, Vw);
  attn_kernel<<<dim3(64, 8), 512, 0, stream>>>(Qw, Kw, Vw, Ow);
  gemm_out<<<dim3(64, 8), 256, 0, stream>>>(Ow, wo, bo, (float*)d_out);
}

// Round 5
// 348.014 us; speedup vs baseline: 1.2575x; 1.0257x over previous
//
#include <hip/hip_runtime.h>
#include <stdint.h>

// ---------- types ----------
typedef __attribute__((ext_vector_type(8))) _Float16 half8;
typedef __attribute__((ext_vector_type(2))) __fp16   fp16x2;
typedef __attribute__((ext_vector_type(4))) float    f32x4;
typedef __attribute__((ext_vector_type(4))) unsigned short us4;

__device__ __forceinline__ unsigned short f2h(float f) {
  union { _Float16 h; unsigned short u; } cv; cv.h = (_Float16)f; return cv.u;
}

// async global->LDS, 16B per lane. lds base wave-uniform; HW adds lane*16.
__device__ __forceinline__ void async_copy16(void* lds, const void* g) {
  __builtin_amdgcn_global_load_lds(
      (__attribute__((address_space(1))) void*)(void*)g,
      (__attribute__((address_space(3))) void*)lds, 16, 0, 0);
}

union U64 { fp16x2 h2[2]; us4 u4; };

// ---------- fused f32 -> f16 conversion (7 regions, 1 launch) ----------
__global__ __launch_bounds__(256) void cvt_all(
    const float* __restrict__ q, const float* __restrict__ k, const float* __restrict__ v,
    const float* __restrict__ wq, const float* __restrict__ wk,
    const float* __restrict__ wv, const float* __restrict__ wo,
    unsigned short* __restrict__ oq, unsigned short* __restrict__ ok,
    unsigned short* __restrict__ ov,
    unsigned short* __restrict__ owq, unsigned short* __restrict__ owk,
    unsigned short* __restrict__ owv, unsigned short* __restrict__ owo) {
  int b = blockIdx.x;
  const float* in; unsigned short* out;
  if      (b < 8192)  { in = q;  out = oq;             }
  else if (b < 16384) { in = k;  out = ok;  b -= 8192; }
  else if (b < 24576) { in = v;  out = ov;  b -= 16384; }
  else if (b < 25600) { in = wq; out = owq; b -= 24576; }
  else if (b < 26624) { in = wk; out = owk; b -= 25600; }
  else if (b < 27648) { in = wv; out = owv; b -= 26624; }
  else                { in = wo; out = owo; b -= 27648; }
  const int i = (b * 256 + threadIdx.x) * 4;
  const float4 x = *(const float4*)(in + i);
  us4 o; o.x = f2h(x.x); o.y = f2h(x.y); o.z = f2h(x.z); o.w = f2h(x.w);
  *(us4*)(out + i) = o;
}

// ---------- 128x128 tile GEMM core: C = A(MxK) * W(NxK)^T, K=1024, BK=32 ----------
__device__ __forceinline__ void gemm128_core(const unsigned short* __restrict__ A,
                                             const unsigned short* __restrict__ Bw,
                                             int m0, int n0,
                                             unsigned short* As, unsigned short* Bs,
                                             f32x4 acc[4][4]) {
  const int tid  = threadIdx.x;
  const int w    = tid >> 6;
  const int l15  = tid & 15;
  const int quad = (tid >> 4) & 3;
  const int w0 = w & 1, w1 = w >> 1;
  const f32x4 zero4 = {0.f, 0.f, 0.f, 0.f};
#pragma unroll
  for (int mt = 0; mt < 4; ++mt)
#pragma unroll
    for (int nt = 0; nt < 4; ++nt) acc[mt][nt] = zero4;

  int srcR[2], srcC[2];
#pragma unroll
  for (int c = 0; c < 2; ++c) {
    const int idx = c * 256 + tid;
    srcR[c] = idx >> 2;
    srcC[c] = (idx & 3) ^ (srcR[c] & 3) ^ ((srcR[c] >> 2) & 3);
  }
  const int cs = quad ^ (l15 & 3) ^ (l15 >> 2);

  for (int k0 = 0; k0 < 1024; k0 += 32) {
    __syncthreads();
#pragma unroll
    for (int c = 0; c < 2; ++c) {
      async_copy16((char*)As + c * 4096 + w * 1024,
                   A  + (m0 + srcR[c]) * 1024 + k0 + srcC[c] * 8);
      async_copy16((char*)Bs + c * 4096 + w * 1024,
                   Bw + (n0 + srcR[c]) * 1024 + k0 + srcC[c] * 8);
    }
    __syncthreads();
    half8 af[4], bf[4];
#pragma unroll
    for (int mt = 0; mt < 4; ++mt)
      af[mt] = *(const half8*)(As + (w1 * 64 + mt * 16 + l15) * 32 + cs * 8);
#pragma unroll
    for (int nt = 0; nt < 4; ++nt)
      bf[nt] = *(const half8*)(Bs + (w0 * 64 + nt * 16 + l15) * 32 + cs * 8);
#pragma unroll
    for (int mt = 0; mt < 4; ++mt)
#pragma unroll
      for (int nt = 0; nt < 4; ++nt)
        acc[mt][nt] = __builtin_amdgcn_mfma_f32_16x16x32_f16(af[mt], bf[nt], acc[mt][nt], 0, 0, 0);
  }
}

// ---------- QKV projection; z selects Q/K/V. Q is pre-scaled by 0.125*log2(e). ----------
__global__ __launch_bounds__(256) void gemm_qkv(
    const unsigned short* __restrict__ Xq, const unsigned short* __restrict__ Xk,
    const unsigned short* __restrict__ Xv,
    const unsigned short* __restrict__ Wq, const unsigned short* __restrict__ Wk,
    const unsigned short* __restrict__ Wv,
    const float* __restrict__ bq, const float* __restrict__ bk, const float* __restrict__ bv,
    unsigned short* __restrict__ Qo, unsigned short* __restrict__ Ko,
    unsigned short* __restrict__ Vo) {
  __shared__ __align__(16) unsigned short As[128 * 32];
  __shared__ __align__(16) unsigned short Bs[128 * 32];
  const int z = blockIdx.z;
  const unsigned short* A = (z == 0) ? Xq : (z == 1) ? Xk : Xv;
  const unsigned short* W = (z == 0) ? Wq : (z == 1) ? Wk : Wv;
  const float* bias = (z == 0) ? bq : (z == 1) ? bk : bv;
  const int m0 = blockIdx.x * 128, n0 = blockIdx.y * 128;
  f32x4 acc[4][4];
  gemm128_core(A, W, m0, n0, As, Bs, acc);

  const int tid = threadIdx.x;
  const int w = tid >> 6, l15 = tid & 15, quad = (tid >> 4) & 3;
  const int w0 = w & 1, w1 = w >> 1;
  const float qscale = (z == 0) ? 0.18033688011112042f : 1.0f;  // 0.125*log2(e)
#pragma unroll
  for (int mt = 0; mt < 4; ++mt) {
    const int mbase = m0 + w1 * 64 + mt * 16 + quad * 4;  // global row = b*2048+s
    const int bb = mbase >> 11, s = mbase & 2047;
#pragma unroll
    for (int nt = 0; nt < 4; ++nt) {
      const int col = n0 + w0 * 64 + nt * 16 + l15;
      const float badd = bias[col];
      const int h = col >> 6, d = col & 63;
      if (z < 2) {
        unsigned short* dst = (z == 0) ? Qo : Ko;
#pragma unroll
        for (int r = 0; r < 4; ++r)
          dst[((bb * 16 + h) * 2048 + (s + r)) * 64 + d] = f2h((acc[mt][nt][r] + badd) * qscale);
      } else {
        us4 pk;
#pragma unroll
        for (int r = 0; r < 4; ++r) pk[r] = f2h(acc[mt][nt][r] + badd);
        *(us4*)(Vo + ((bb * 16 + h) * 64 + d) * 2048 + s) = pk;
      }
    }
  }
}

// ---------- flash attention, transposed-score orientation, 16-wave blocks ----------
// grid (64 bh, 8 qtiles) x 1024 threads: 256 Q rows/block, ONE 16-row strip per wave.
// 2 blocks/CU = 32 waves/CU = 100% wave slots (round-4 was grid-limited to 16 waves:
// MfmaUtil 28 / VALUBusy 58 / Occupancy 35 with HBM at 4.5% -> latency-bound).
// __launch_bounds__(1024, 8): 8 waves/EU -> 64-VGPR cap; per-wave state halved
// (acc[4]+lsum+qf ~28 regs) so no spill (round-3 tripwire: watch WRITE_SIZE).
// bh on blockIdx.x keeps all q-tiles of a bh on one XCD (FETCH 25MB, L2-resident).
// K/V staged by thread role: tid<512 stages K, tid>=512 stages V (one
// global_load_lds per thread per tile). Double-buffered; single __syncthreads
// per tile (implicit vmcnt(0) drains next tile AFTER this tile's MFMAs).
// S^T = K*Q^T so C-layout col = q-row = l15 everywhere; row sums via ones-A-frag
// MFMA; no shuffles.
#define PKS 40  // P^T key stride (halves) for a 32-key half: 80B rows, bank-clean
__global__ __launch_bounds__(1024, 8) void attn_kernel(const unsigned short* __restrict__ Q,
                                                       const unsigned short* __restrict__ K,
                                                       const unsigned short* __restrict__ Vt,
                                                       unsigned short* __restrict__ O) {
  __shared__ __align__(16) unsigned short Ps[10240];       // 16 waves x 640 halves = 20,480B
  __shared__ __align__(16) unsigned short Ks[2][64 * 64];  // double-buffered
  __shared__ __align__(16) unsigned short Vs[2][64 * 64];  // [d][key], double-buffered
  const int bh = blockIdx.x, qt = blockIdx.y;
  const int tid = threadIdx.x;
  const int w = tid >> 6, l15 = tid & 15, quad = (tid >> 4) & 3;
  const int cq0 = quad ^ (l15 & 7), cq1 = (4 + quad) ^ (l15 & 7);

  // staging roles: waves 0-7 stage K, waves 8-15 stage V. 512 lanes x 16B = full tile.
  const int t9 = tid & 511;
  const int srcR = t9 >> 3;
  const int srcC = (t9 & 7) ^ (srcR & 7);
  const bool doK = (tid < 512);
  const int w8 = w & 7;

  const unsigned short* Kg0 = K + bh * 2048 * 64;
  const unsigned short* Vg0 = Vt + bh * 131072;

  auto stage_kv = [&](int t, int buf) {
    if (doK)
      async_copy16((char*)Ks + buf * 8192 + w8 * 1024, Kg0 + t * 4096 + srcR * 64 + srcC * 8);
    else
      async_copy16((char*)Vs + buf * 8192 + w8 * 1024, Vg0 + t * 64 + srcR * 2048 + srcC * 8);
  };

  // Q B-frags direct from global: qf[h] = Q[row][h*32 + quad*8 .. +7], 16B aligned.
  stage_kv(0, 0);
  const unsigned short* Qg = Q + (bh * 2048 + qt * 256) * 64;
  half8 qf[2];
  {
    const int row = w * 16 + l15;
    qf[0] = *(const half8*)(Qg + row * 64 + quad * 8);
    qf[1] = *(const half8*)(Qg + row * 64 + 32 + quad * 8);
  }
  __syncthreads();  // drain K/V tile0

  const f32x4 zero4 = {0.f, 0.f, 0.f, 0.f};
  f32x4 acc[4];   // O^T: acc[dt], rows d=dt*16+quad*4+r, col qrow=l15
  f32x4 lsum = zero4;
#pragma unroll
  for (int dt = 0; dt < 4; ++dt) acc[dt] = zero4;
  half8 ones;
#pragma unroll
  for (int i = 0; i < 8; ++i) ones[i] = (_Float16)1.0f;

  unsigned short* Pw = Ps + w * 640;  // 16 rows x PKS halves, wave-private

  for (int kt = 0; kt < 32; ++kt) {
    if (kt < 31) stage_kv(kt + 1, (kt + 1) & 1);  // issue next tile NOW; drains at barrier below
    const unsigned short* Kc = Ks[kt & 1];
    const unsigned short* Vc = Vs[kt & 1];

    // per 32-key half: S^T (2 nt2) -> exp2 -> P^T half-buffer -> PV for that half.
#pragma unroll
    for (int h = 0; h < 2; ++h) {
#pragma unroll
      for (int nt2 = 0; nt2 < 2; ++nt2) {
        const int rk = (h * 2 + nt2) * 16 + l15;
        half8 ak0 = *(const half8*)(Kc + rk * 64 + cq0 * 8);
        half8 ak1 = *(const half8*)(Kc + rk * 64 + cq1 * 8);
        f32x4 z = zero4;
        z = __builtin_amdgcn_mfma_f32_16x16x32_f16(ak0, qf[0], z, 0, 0, 0);
        z = __builtin_amdgcn_mfma_f32_16x16x32_f16(ak1, qf[1], z, 0, 0, 0);
        U64 u;
        u.h2[0] = __builtin_amdgcn_cvt_pkrtz(__builtin_exp2f(z[0]), __builtin_exp2f(z[1]));
        u.h2[1] = __builtin_amdgcn_cvt_pkrtz(__builtin_exp2f(z[2]), __builtin_exp2f(z[3]));
        // keys (within half) nt2*16+quad*4+r at P^T[qrow=l15][key]
        *(us4*)(Pw + l15 * PKS + nt2 * 16 + quad * 4) = u.u4;
      }
      // PV for this 32-key half: O^T += V^T * P^T ; l via ones-A-frag MFMA
      const int ch = h ? cq1 : cq0;
      half8 bp = *(const half8*)(Pw + l15 * PKS + quad * 8);
      lsum = __builtin_amdgcn_mfma_f32_16x16x32_f16(ones, bp, lsum, 0, 0, 0);
#pragma unroll
      for (int dt = 0; dt < 4; ++dt) {
        half8 av = *(const half8*)(Vc + (dt * 16 + l15) * 64 + ch * 8);
        acc[dt] = __builtin_amdgcn_mfma_f32_16x16x32_f16(av, bp, acc[dt], 0, 0, 0);
      }
    }
    __syncthreads();  // drains next-tile loads (vmcnt 0) + protects K/V buffers
  }

  // epilogue: O (B,S,1024) f16; col(l15)=qrow for both acc and lsum -> no shuffles
  const int b = bh >> 4, hd = bh & 15;
  const float rv = 1.0f / lsum[0];
  const int sg = qt * 256 + w * 16 + l15;
  unsigned short* Orow = O + (b * 2048 + sg) * 1024 + hd * 64;
#pragma unroll
  for (int dt = 0; dt < 4; ++dt) {
    U64 u;
    u.h2[0] = __builtin_amdgcn_cvt_pkrtz(acc[dt][0] * rv, acc[dt][1] * rv);
    u.h2[1] = __builtin_amdgcn_cvt_pkrtz(acc[dt][2] * rv, acc[dt][3] * rv);
    *(us4*)(Orow + dt * 16 + quad * 4) = u.u4;
  }
}

// ---------- output projection -> f32 ----------
__global__ __launch_bounds__(256) void gemm_out(const unsigned short* __restrict__ A,
                                                const unsigned short* __restrict__ W,
                                                const float* __restrict__ bias,
                                                float* __restrict__ out) {
  __shared__ __align__(16) unsigned short As[128 * 32];
  __shared__ __align__(16) unsigned short Bs[128 * 32];
  const int m0 = blockIdx.x * 128, n0 = blockIdx.y * 128;
  f32x4 acc[4][4];
  gemm128_core(A, W, m0, n0, As, Bs, acc);
  const int tid = threadIdx.x;
  const int w = tid >> 6, l15 = tid & 15, quad = (tid >> 4) & 3;
  const int w0 = w & 1, w1 = w >> 1;
#pragma unroll
  for (int mt = 0; mt < 4; ++mt) {
    const int mbase = m0 + w1 * 64 + mt * 16 + quad * 4;
#pragma unroll
    for (int nt = 0; nt < 4; ++nt) {
      const int col = n0 + w0 * 64 + nt * 16 + l15;
      const float badd = bias[col];
#pragma unroll
      for (int r = 0; r < 4; ++r)
        out[(mbase + r) * 1024 + col] = acc[mt][nt][r] + badd;
    }
  }
}

// ---------- launch ----------
extern "C" void kernel_launch(void* const* d_in, const int* in_sizes, int n_in,
                              void* d_out, int out_size, void* d_ws, size_t ws_size,
                              hipStream_t stream) {
  const float* query = (const float*)d_in[0];
  const float* key_  = (const float*)d_in[1];
  const float* value = (const float*)d_in[2];
  const float* Wq = (const float*)d_in[3];
  const float* bq = (const float*)d_in[4];
  const float* Wk = (const float*)d_in[5];
  const float* bk = (const float*)d_in[6];
  const float* Wv = (const float*)d_in[7];
  const float* bv = (const float*)d_in[8];
  const float* Wo = (const float*)d_in[9];
  const float* bo = (const float*)d_in[10];

  unsigned short* ws = (unsigned short*)d_ws;
  unsigned short* xq = ws;               // (B,S,D) f16 of query
  unsigned short* xk = xq + 8388608;
  unsigned short* xv = xk + 8388608;
  unsigned short* wq = xv + 8388608;
  unsigned short* wk = wq + 1048576;
  unsigned short* wv = wk + 1048576;
  unsigned short* wo = wv + 1048576;
  unsigned short* Qw = wo + 1048576;     // (B,H,S,64), pre-scaled by 0.125*log2e
  unsigned short* Kw = Qw + 8388608;     // (B,H,S,64)
  unsigned short* Vw = Kw + 8388608;     // (B,H,64,S) transposed
  unsigned short* Ow = xq;               // reuse query-f16 region for attn output

  cvt_all<<<28672, 256, 0, stream>>>(query, key_, value, Wq, Wk, Wv, Wo,
                                     xq, xk, xv, wq, wk, wv, wo);
  gemm_qkv<<<dim3(64, 8, 3), 256, 0, stream>>>(xq, xk, xv, wq, wk, wv, bq, bk, bv, Qw, Kw, Vw);
  attn_kernel<<<dim3(64, 8), 1024, 0, stream>>>(Qw, Kw, Vw, Ow);
  gemm_out<<<dim3(64, 8), 256, 0, stream>>>(Ow, wo, bo, (float*)d_out);
}